// Round 1
// 232.276 us; speedup vs baseline: 1.0652x; 1.0652x over previous
//
#include <hip/hip_runtime.h>
#include <hip/hip_bf16.h>

// Problem constants
#define NN 128
#define CC 64
#define TT 128
#define VV 25
#define RR 8
#define HH 12
#define TPAD 132       // xs row stride (dwords): %4==0 for b128 align; /4=33 odd -> quads cycle all 8
#define RELP 28        // padded v-stride of rel rows (16B-aligned quads)
#define RELR (VV*RELP)     // 700   floats per (n,r)
#define RELN (RR*RELR)     // 5600  floats per n

// ---------------------------------------------------------------------------
// Kernel A: xm[n,c,v] = mean over T of x[n,c,t,v].  One block per (n,c).
// (unchanged — x is L3-resident, kernel is near the BW floor)
// ---------------------------------------------------------------------------
__global__ __launch_bounds__(256) void kA_tmean(const float* __restrict__ x,
                                                float* __restrict__ xm) {
    const int blk = blockIdx.x;            // n*CC + c
    const int tid = threadIdx.x;
    __shared__ float st[TT * VV];          // 3200 floats
    __shared__ float ps[8 * VV];

    const float4* xb4 = (const float4*)(x + (size_t)blk * (TT * VV));
    float4* st4 = (float4*)st;
    for (int i = tid; i < (TT * VV) / 4; i += 256) st4[i] = xb4[i];
    __syncthreads();

    if (tid < 200) {
        const int v = tid % VV, tseg = tid / VV;   // 8 segments of 16 t
        float s = 0.f;
        const int base = tseg * 16 * VV + v;
#pragma unroll
        for (int i = 0; i < 16; i++) s += st[base + i * VV];
        ps[tseg * VV + v] = s;
    }
    __syncthreads();
    if (tid < VV) {
        float s = 0.f;
#pragma unroll
        for (int k = 0; k < 8; k++) s += ps[k * VV + tid];
        xm[(size_t)blk * VV + tid] = s * (1.f / TT);
    }
}

// ---------------------------------------------------------------------------
// Kernel B: per-n small pipeline. One block per n.
// rel is now written PADDED: [n][r][u][28], pad cols (v>=25) = 0, so kC can
// read aligned float4 quads.
// ---------------------------------------------------------------------------
__global__ __launch_bounds__(256) void kB_small(
    const float* __restrict__ xm,
    const float* __restrict__ w1, const float* __restrict__ b1,
    const float* __restrict__ w2, const float* __restrict__ b2,
    const float* __restrict__ sw1, const float* __restrict__ sb1,
    const float* __restrict__ sw2, const float* __restrict__ sb2,
    float* __restrict__ a_out, float* __restrict__ rel_out) {
    const int n = blockIdx.x;
    const int tid = threadIdx.x;
    __shared__ float lxm[CC * VV];   // 1600
    __shared__ float ls[VV];
    __shared__ float lh[HH];
    __shared__ float l1[RR * VV];
    __shared__ float l2[RR * VV];

    for (int i = tid; i < CC * VV; i += 256) lxm[i] = xm[(size_t)n * CC * VV + i];
    __syncthreads();

    if (tid < VV) {
        float s = 0.f;
        for (int c = 0; c < CC; c++) s += lxm[c * VV + tid];
        ls[tid] = s * (1.f / CC);
    }
    if (tid < RR * VV) {
        int r = tid / VV, v = tid % VV;
        float s1 = b1[r], s2 = b2[r];
        for (int c = 0; c < CC; c++) {
            float xv = lxm[c * VV + v];
            s1 += w1[r * CC + c] * xv;
            s2 += w2[r * CC + c] * xv;
        }
        l1[tid] = s1;
        l2[tid] = s2;
    }
    __syncthreads();

    if (tid < HH) {
        float h = sb1[tid];
        for (int v = 0; v < VV; v++) h += sw1[tid * VV + v] * ls[v];
        lh[tid] = fmaxf(h, 0.f);
    }
    __syncthreads();

    if (tid < VV) {
        float z = sb2[tid];
        for (int j = 0; j < HH; j++) z += sw2[tid * HH + j] * lh[j];
        a_out[(size_t)n * VV + tid] = 1.f / (1.f + expf(-z));
    }

    // padded rel: [r][u][28]; pad cols zero (finite, NaN-free for kC quads)
    for (int idx = tid; idx < RELN; idx += 256) {
        int r = idx / RELR;
        int rem = idx - r * RELR;
        int u = rem / RELP;
        int v = rem - u * RELP;
        float val = 0.f;
        if (v < VV) val = tanhf(l1[r * VV + u] - l2[r * VV + v]);
        rel_out[(size_t)n * RELN + idx] = val;
    }
}

// ---------------------------------------------------------------------------
// Kernel C: per-(n,c) output tile.
//  Ad'[u,v] = (b4[c] + A[u,v] + sum_r w4[c,r]*rel[n,r,u,v]) * a[n,v]
//  out[t,u] = sum_v Ad'[u,v] * x[n,c,t,v]
// v3 (VALU-cut):
//  - P1: quad threads (175), aligned b128 rel loads from padded rel,
//        b128 ad writes. No div-by-28, no masking (pad cols unread).
//  - P1b: x loads hoisted to kernel entry; incremental (t,v) scatter
//        indexing (no div/mod in the loop).
//  - P2: 6 full v-quads + scalar v=24 tail (no phantom v work, xs rows
//        25..27 and their zero-fill deleted); ug==6 takes a dedicated
//        single-u path (u=24), so ad needs only 25 rows.
//  - Epilogue: u-guard deleted (statically in-range), staging/copy as
//        before (R2 lesson: direct strided global stores were the kernel).
// ---------------------------------------------------------------------------
__global__ __launch_bounds__(256) void kC_main(
    const float* __restrict__ x, const float* __restrict__ A,
    const float* __restrict__ w4, const float* __restrict__ b4,
    const float* __restrict__ rel, const float* __restrict__ av,
    float* __restrict__ out) {
    const int blk = blockIdx.x;    // n*CC + c
    const int n = blk >> 6;
    const int c = blk & (CC - 1);
    const int tid = threadIdx.x;

    __shared__ __align__(16) float ad[VV * RELP];    // 700 dwords = 2800 B
    __shared__ __align__(16) float xs[VV * TPAD];    // 3300 dwords = 13200 B (>=3200 for os reuse)
    float* os = xs;                                  // output staging, reuses xs after phase 2

    // --- hoist the x-tile loads (longest latency) to the very top ---
    const float4* xb4 = (const float4*)(x + (size_t)blk * (TT * VV));
    float4 q0 = xb4[tid];
    float4 q1 = xb4[tid + 256];
    float4 q2 = xb4[tid + 512];
    float4 q3;
    if (tid < 32) q3 = xb4[tid + 768];   // 800 float4 total

    float w4r[RR];
#pragma unroll
    for (int r = 0; r < RR; r++) w4r[r] = w4[c * RR + r];
    const float b4c = b4[c];

    // phase 1: Ad' quads. 175 threads = 25 u-rows x 7 v-quads.
    if (tid < VV * 7) {
        const int u = tid / 7;
        const int v0 = (tid - u * 7) * 4;
        const float* rp = rel + (size_t)n * RELN + u * RELP + v0;
        float s0 = b4c, s1 = b4c, s2 = b4c, s3 = b4c;
#pragma unroll
        for (int r = 0; r < RR; r++) {
            const float4 rq = *(const float4*)(rp + r * RELR);
            s0 += w4r[r] * rq.x;
            s1 += w4r[r] * rq.y;
            s2 += w4r[r] * rq.z;
            s3 += w4r[r] * rq.w;
        }
        // clamp A/av column index (only guards the v0=24 quad's pad lanes;
        // those results land in ad cols 25..27 which are never read)
        const int c0 = v0;
        const int c1 = min(v0 + 1, VV - 1);
        const int c2 = min(v0 + 2, VV - 1);
        const int c3 = min(v0 + 3, VV - 1);
        const float* Ar = A + u * VV;
        const float* avp = av + (size_t)n * VV;
        float4 o;
        o.x = (s0 + Ar[c0]) * avp[c0];
        o.y = (s1 + Ar[c1]) * avp[c1];
        o.z = (s2 + Ar[c2]) * avp[c2];
        o.w = (s3 + Ar[c3]) * avp[c3];
        *(float4*)&ad[u * RELP + v0] = o;
    }

    // phase 1b: scatter x tile TRANSPOSED into xs[v][t], incremental indexing.
    // element index advances by 1024 per pass: t += 40, v -= 1 (wrap at 0).
    {
        int lin = tid * 4;
        int t = lin / VV;              // one magic-div, hoisted out of the loop
        int v = lin - t * VV;
#define SCAT4(q)                                              \
        {                                                     \
            int tt = t, vv = v;                               \
            xs[vv * TPAD + tt] = (q).x;                       \
            vv++; if (vv == VV) { vv = 0; tt++; }             \
            xs[vv * TPAD + tt] = (q).y;                       \
            vv++; if (vv == VV) { vv = 0; tt++; }             \
            xs[vv * TPAD + tt] = (q).z;                       \
            vv++; if (vv == VV) { vv = 0; tt++; }             \
            xs[vv * TPAD + tt] = (q).w;                       \
        }
#define ADV1024() { v += 24; t += 40; if (v >= VV) { v -= VV; t += 1; } }
        SCAT4(q0); ADV1024();
        SCAT4(q1); ADV1024();
        SCAT4(q2); ADV1024();
        if (tid < 32) SCAT4(q3);
#undef SCAT4
#undef ADV1024
    }
    __syncthreads();

    // phase 2: 4x4 register tile, 6 full v-quads + v=24 tail
    const int ug = tid >> 5;       // 0..7 (0..5 full, 6 = u-row 24, 7 idle)
    const int tg = tid & 31;       // 0..31
    const int u0 = ug * 4;
    const int t0 = tg * 4;
    float acc[4][4];               // acc[dt][j]
#pragma unroll
    for (int dt = 0; dt < 4; dt++)
#pragma unroll
        for (int j = 0; j < 4; j++) acc[dt][j] = 0.f;

    if (ug < 6) {
#pragma unroll
        for (int vb = 0; vb < 6; vb++) {
            float4 a4[4];          // a4[j]  = ad[u0+j][vb*4 .. +3]  (2-addr broadcast)
            float4 x4[4];          // x4[vi] = xs[vb*4+vi][t0 .. t0+3] (conflict-free)
#pragma unroll
            for (int j = 0; j < 4; j++) a4[j] = *(const float4*)&ad[(u0 + j) * RELP + vb * 4];
#pragma unroll
            for (int vi = 0; vi < 4; vi++) x4[vi] = *(const float4*)&xs[(vb * 4 + vi) * TPAD + t0];
            const float* xv = (const float*)&x4[0];
#pragma unroll
            for (int dt = 0; dt < 4; dt++) {
#pragma unroll
                for (int j = 0; j < 4; j++) {
                    acc[dt][j] += a4[j].x * xv[0 * 4 + dt];
                    acc[dt][j] += a4[j].y * xv[1 * 4 + dt];
                    acc[dt][j] += a4[j].z * xv[2 * 4 + dt];
                    acc[dt][j] += a4[j].w * xv[3 * 4 + dt];
                }
            }
        }
        // tail: v = 24
        {
            const float a0 = ad[(u0 + 0) * RELP + 24];
            const float a1 = ad[(u0 + 1) * RELP + 24];
            const float a2 = ad[(u0 + 2) * RELP + 24];
            const float a3 = ad[(u0 + 3) * RELP + 24];
            float4 xt = *(const float4*)&xs[24 * TPAD + t0];
            const float* xtp = (const float*)&xt;
#pragma unroll
            for (int dt = 0; dt < 4; dt++) {
                const float xvd = xtp[dt];
                acc[dt][0] += a0 * xvd;
                acc[dt][1] += a1 * xvd;
                acc[dt][2] += a2 * xvd;
                acc[dt][3] += a3 * xvd;
            }
        }
    } else if (ug == 6) {
        // single real u-row (u = 24), j = 0 only
#pragma unroll
        for (int vb = 0; vb < 6; vb++) {
            float4 a40 = *(const float4*)&ad[24 * RELP + vb * 4];
            float4 x4[4];
#pragma unroll
            for (int vi = 0; vi < 4; vi++) x4[vi] = *(const float4*)&xs[(vb * 4 + vi) * TPAD + t0];
            const float* xv = (const float*)&x4[0];
#pragma unroll
            for (int dt = 0; dt < 4; dt++) {
                acc[dt][0] += a40.x * xv[0 * 4 + dt];
                acc[dt][0] += a40.y * xv[1 * 4 + dt];
                acc[dt][0] += a40.z * xv[2 * 4 + dt];
                acc[dt][0] += a40.w * xv[3 * 4 + dt];
            }
        }
        {
            const float a0 = ad[24 * RELP + 24];
            float4 xt = *(const float4*)&xs[24 * TPAD + t0];
            const float* xtp = (const float*)&xt;
#pragma unroll
            for (int dt = 0; dt < 4; dt++) acc[dt][0] += a0 * xtp[dt];
        }
    }
    __syncthreads();   // all xs reads done; safe to overwrite with os

    // epilogue a: scatter acc into os with exact output-tile layout (no guard)
    if (ug < 6) {
#pragma unroll
        for (int dt = 0; dt < 4; dt++)
#pragma unroll
            for (int j = 0; j < 4; j++) os[(t0 + dt) * VV + u0 + j] = acc[dt][j];
    } else if (ug == 6) {
#pragma unroll
        for (int dt = 0; dt < 4; dt++) os[(t0 + dt) * VV + 24] = acc[dt][0];
    }
    __syncthreads();

    // epilogue b: coalesced float4 stores of the whole 12.8 KB tile
    float4* ob4 = (float4*)(out + (size_t)blk * (TT * VV));
    const float4* os4 = (const float4*)os;
    ob4[tid]       = os4[tid];
    ob4[tid + 256] = os4[tid + 256];
    ob4[tid + 512] = os4[tid + 512];
    if (tid < 32) ob4[tid + 768] = os4[tid + 768];
}

// ---------------------------------------------------------------------------
extern "C" void kernel_launch(void* const* d_in, const int* in_sizes, int n_in,
                              void* d_out, int out_size, void* d_ws, size_t ws_size,
                              hipStream_t stream) {
    const float* x   = (const float*)d_in[0];
    const float* A   = (const float*)d_in[1];
    const float* w1  = (const float*)d_in[2];
    const float* b1  = (const float*)d_in[3];
    const float* w2  = (const float*)d_in[4];
    const float* b2  = (const float*)d_in[5];
    const float* w4  = (const float*)d_in[6];
    const float* b4  = (const float*)d_in[7];
    const float* sw1 = (const float*)d_in[8];
    const float* sb1 = (const float*)d_in[9];
    const float* sw2 = (const float*)d_in[10];
    const float* sb2 = (const float*)d_in[11];
    float* out = (float*)d_out;

    float* ws = (float*)d_ws;
    float* xm  = ws;                                 // N*C*V      = 204800
    float* a_s = xm + (size_t)NN * CC * VV;          // N*V        = 3200
    float* rel = a_s + (size_t)NN * VV;              // N*R*V*28   = 716800

    kA_tmean<<<NN * CC, 256, 0, stream>>>(x, xm);
    kB_small<<<NN, 256, 0, stream>>>(xm, w1, b1, w2, b2, sw1, sb1, sw2, sb2, a_s, rel);
    kC_main<<<NN * CC, 256, 0, stream>>>(x, A, w4, b4, rel, a_s, out);
}

// Round 3
// 229.917 us; speedup vs baseline: 1.0761x; 1.0103x over previous
//
#include <hip/hip_runtime.h>
#include <hip/hip_bf16.h>

// Problem constants
#define NN 128
#define CC 64
#define TT 128
#define VV 25
#define RR 8
#define HH 12
#define RELP 28        // padded v-stride of rel rows (16B-aligned quads)
#define RELR (VV*RELP)     // 700   floats per (n,r)
#define RELN (RR*RELR)     // 5600  floats per n
#define KP 40          // bf16 k-stride in LDS: 80B rows -> <=2-way banks, 16B aligned

typedef __attribute__((ext_vector_type(8))) short short8;
typedef __attribute__((ext_vector_type(4))) float f32x4;

// portable bf16 (RNE) split helpers — bit ops only, no type-API dependence
__device__ __forceinline__ unsigned int f2bf(float f) {
    unsigned int u = __builtin_bit_cast(unsigned int, f);
    return (u + 0x7FFFu + ((u >> 16) & 1u)) >> 16;
}
__device__ __forceinline__ float bf2f(unsigned int b) {
    return __builtin_bit_cast(float, b << 16);
}

// ---------------------------------------------------------------------------
// Kernel A: xm[n,c,v] = mean over T of x[n,c,t,v].  One block per (n,c).
// (unchanged — at the BW floor)
// ---------------------------------------------------------------------------
__global__ __launch_bounds__(256) void kA_tmean(const float* __restrict__ x,
                                                float* __restrict__ xm) {
    const int blk = blockIdx.x;            // n*CC + c
    const int tid = threadIdx.x;
    __shared__ float st[TT * VV];          // 3200 floats
    __shared__ float ps[8 * VV];

    const float4* xb4 = (const float4*)(x + (size_t)blk * (TT * VV));
    float4* st4 = (float4*)st;
    for (int i = tid; i < (TT * VV) / 4; i += 256) st4[i] = xb4[i];
    __syncthreads();

    if (tid < 200) {
        const int v = tid % VV, tseg = tid / VV;   // 8 segments of 16 t
        float s = 0.f;
        const int base = tseg * 16 * VV + v;
#pragma unroll
        for (int i = 0; i < 16; i++) s += st[base + i * VV];
        ps[tseg * VV + v] = s;
    }
    __syncthreads();
    if (tid < VV) {
        float s = 0.f;
#pragma unroll
        for (int k = 0; k < 8; k++) s += ps[k * VV + tid];
        xm[(size_t)blk * VV + tid] = s * (1.f / TT);
    }
}

// ---------------------------------------------------------------------------
// Kernel B: per-n small pipeline. One block per n. rel written PADDED
// [n][r][u][28] (pad cols v>=25 = 0) so kC reads aligned float4 quads.
// ---------------------------------------------------------------------------
__global__ __launch_bounds__(256) void kB_small(
    const float* __restrict__ xm,
    const float* __restrict__ w1, const float* __restrict__ b1,
    const float* __restrict__ w2, const float* __restrict__ b2,
    const float* __restrict__ sw1, const float* __restrict__ sb1,
    const float* __restrict__ sw2, const float* __restrict__ sb2,
    float* __restrict__ a_out, float* __restrict__ rel_out) {
    const int n = blockIdx.x;
    const int tid = threadIdx.x;
    __shared__ float lxm[CC * VV];   // 1600
    __shared__ float ls[VV];
    __shared__ float lh[HH];
    __shared__ float l1[RR * VV];
    __shared__ float l2[RR * VV];

    for (int i = tid; i < CC * VV; i += 256) lxm[i] = xm[(size_t)n * CC * VV + i];
    __syncthreads();

    if (tid < VV) {
        float s = 0.f;
        for (int c = 0; c < CC; c++) s += lxm[c * VV + tid];
        ls[tid] = s * (1.f / CC);
    }
    if (tid < RR * VV) {
        int r = tid / VV, v = tid % VV;
        float s1 = b1[r], s2 = b2[r];
        for (int c = 0; c < CC; c++) {
            float xv = lxm[c * VV + v];
            s1 += w1[r * CC + c] * xv;
            s2 += w2[r * CC + c] * xv;
        }
        l1[tid] = s1;
        l2[tid] = s2;
    }
    __syncthreads();

    if (tid < HH) {
        float h = sb1[tid];
        for (int v = 0; v < VV; v++) h += sw1[tid * VV + v] * ls[v];
        lh[tid] = fmaxf(h, 0.f);
    }
    __syncthreads();

    if (tid < VV) {
        float z = sb2[tid];
        for (int j = 0; j < HH; j++) z += sw2[tid * HH + j] * lh[j];
        a_out[(size_t)n * VV + tid] = 1.f / (1.f + expf(-z));
    }

    // padded rel: [r][u][28]; pad cols zero (finite, NaN-free for kC quads)
    for (int idx = tid; idx < RELN; idx += 256) {
        int r = idx / RELR;
        int rem = idx - r * RELR;
        int u = rem / RELP;
        int v = rem - u * RELP;
        float val = 0.f;
        if (v < VV) val = tanhf(l1[r * VV + u] - l2[r * VV + v]);
        rel_out[(size_t)n * RELN + idx] = val;
    }
}

// ---------------------------------------------------------------------------
// Kernel C: per-(n,c) output tile.
//  Ad'[u,v] = (b4[c] + A[u,v] + sum_r w4[c,r]*rel[n,r,u,v]) * a[n,v]
//  out[t,u] = sum_v Ad'[u,v] * x[n,c,t,v]
// v5 (MFMA, NaN fix): phase 2 is a 128x25x25 GEMM via mfma_f32_16x16x32_bf16
// with split-bf16 precision (out = xh*adh + xh*adl + xl*adh).
// FIX vs v4: adb k-cols 28..39 of real rows (u=0..24) were uninitialized LDS;
// MFMA reads k=0..31, and 0 (x side) * garbage-NaN (adb side) = NaN. Now
// explicitly zeroed (150-thread write, disjoint from quad writes, no extra
// barrier). Also clamped the potential 4B-OOB x read at the last element.
// ---------------------------------------------------------------------------
__global__ __launch_bounds__(256) void kC_main(
    const float* __restrict__ x, const float* __restrict__ A,
    const float* __restrict__ w4, const float* __restrict__ b4,
    const float* __restrict__ rel, const float* __restrict__ av,
    float* __restrict__ out) {
    const int blk = blockIdx.x;    // n*CC + c
    const int n = blk >> 6;
    const int c = blk & (CC - 1);
    const int tid = threadIdx.x;

    __shared__ __align__(16) unsigned short xsb[2][TT * KP];   // hi, lo
    __shared__ __align__(16) unsigned short adb[2][32 * KP];   // hi, lo
    float* os = (float*)&xsb[0][0];   // 12800 B output staging overlays xsb (20480 B)

    const float* xg = x + (size_t)blk * (TT * VV);

    // --- phase 1b: stage x as bf16 hi/lo, [t][KP], packed-pair u32 writes ---
    // unit idx = t*13 + p covers v-pairs (2p, 2p+1); 1664 units, 6.5/thread.
    {
        int t = tid / 13;
        int p = tid - t * 13;
#pragma unroll
        for (int it = 0; it < 7; ++it) {
            if (it < 6 || t < TT) {
                const float* row = xg + t * VV + 2 * p;
                float f0 = row[0];
                float f1 = row[(p < 12) ? 1 : 0];   // in-bounds read
                if (p >= 12) f1 = 0.f;              // v=25 k-pad -> 0
                unsigned int h0 = f2bf(f0);
                unsigned int l0 = f2bf(f0 - bf2f(h0));
                unsigned int h1 = f2bf(f1);
                unsigned int l1 = f2bf(f1 - bf2f(h1));
                *(unsigned int*)&xsb[0][t * KP + 2 * p] = h0 | (h1 << 16);
                *(unsigned int*)&xsb[1][t * KP + 2 * p] = l0 | (l1 << 16);
            }
            p += 9; t += 19;
            if (p >= 13) { p -= 13; ++t; }
        }
        // k-pad v=26..31 -> zero (uint cols 13,14,15)
        for (int i = tid; i < TT * 3; i += 256) {
            int tt = i / 3, q = i - (i / 3) * 3;
            *(unsigned int*)&xsb[0][tt * KP + 26 + 2 * q] = 0u;
            *(unsigned int*)&xsb[1][tt * KP + 26 + 2 * q] = 0u;
        }
    }

    // --- phase 1: Ad' quads -> bf16 hi/lo in adb. 175 threads = 25u x 7vq ---
    {
        float w4r[RR];
#pragma unroll
        for (int r = 0; r < RR; r++) w4r[r] = w4[c * RR + r];
        const float b4c = b4[c];

        if (tid < VV * 7) {
            const int u = tid / 7;
            const int v0 = (tid - u * 7) * 4;
            const float* rp = rel + (size_t)n * RELN + u * RELP + v0;
            float s0 = b4c, s1 = b4c, s2 = b4c, s3 = b4c;
#pragma unroll
            for (int r = 0; r < RR; r++) {
                const float4 rq = *(const float4*)(rp + r * RELR);
                s0 += w4r[r] * rq.x;
                s1 += w4r[r] * rq.y;
                s2 += w4r[r] * rq.z;
                s3 += w4r[r] * rq.w;
            }
            // clamp A/av col index for the v0=24 quad's pad lanes; those land
            // in k-cols 25..27 whose x-side is zero -> no contribution.
            const int c0 = v0;
            const int c1 = min(v0 + 1, VV - 1);
            const int c2 = min(v0 + 2, VV - 1);
            const int c3 = min(v0 + 3, VV - 1);
            const float* Ar = A + u * VV;
            const float* avp = av + (size_t)n * VV;
            float o0 = (s0 + Ar[c0]) * avp[c0];
            float o1 = (s1 + Ar[c1]) * avp[c1];
            float o2 = (s2 + Ar[c2]) * avp[c2];
            float o3 = (s3 + Ar[c3]) * avp[c3];
            unsigned int h0 = f2bf(o0), h1 = f2bf(o1), h2 = f2bf(o2), h3 = f2bf(o3);
            unsigned int l0 = f2bf(o0 - bf2f(h0));
            unsigned int l1 = f2bf(o1 - bf2f(h1));
            unsigned int l2 = f2bf(o2 - bf2f(h2));
            unsigned int l3 = f2bf(o3 - bf2f(h3));
            *(unsigned int*)&adb[0][u * KP + v0]     = h0 | (h1 << 16);
            *(unsigned int*)&adb[0][u * KP + v0 + 2] = h2 | (h3 << 16);
            *(unsigned int*)&adb[1][u * KP + v0]     = l0 | (l1 << 16);
            *(unsigned int*)&adb[1][u * KP + v0 + 2] = l2 | (l3 << 16);
        }
        // FIX: zero the never-written k-tail of real rows u=0..24:
        // uints 14..19 (shorts 28..39). MFMA reads k=28..31; stale LDS there
        // decoding as bf16 Inf/NaN made 0*garbage = NaN.
        if (tid < 25 * 6) {
            int u = tid / 6, q = tid - (tid / 6) * 6;
            *(unsigned int*)&adb[0][u * KP + 28 + 2 * q] = 0u;
            *(unsigned int*)&adb[1][u * KP + 28 + 2 * q] = 0u;
        }
        // n-pad rows u=25..31 -> zero (outputs discarded, keep bits clean)
        for (int i = tid; i < 7 * 20; i += 256) {
            int rr2 = i / 20, cc2 = i - (i / 20) * 20;
            *(unsigned int*)&adb[0][(VV + rr2) * KP + 2 * cc2] = 0u;
            *(unsigned int*)&adb[1][(VV + rr2) * KP + 2 * cc2] = 0u;
        }
    }
    __syncthreads();

    // --- phase 2: MFMA. M=128 (8 m-tiles), N=32 (2 n-tiles), K=32 (1 step).
    // wave w owns m-tiles {2w, 2w+1} x n-tiles {0,1}; 3 split passes.
    const int wid = tid >> 6;
    const int lane = tid & 63;
    const int fr = lane & 15;          // fragment row (m for A, n for B)
    const int fk = (lane >> 4) * 8;    // k offset of this lane's 8 elements

    f32x4 acc[2][2] = {};
    short8 ah[2], al[2], bh[2], bl[2];
#pragma unroll
    for (int mi = 0; mi < 2; ++mi) {
        const int m = (wid * 2 + mi) * 16 + fr;
        ah[mi] = *(const short8*)&xsb[0][m * KP + fk];
        al[mi] = *(const short8*)&xsb[1][m * KP + fk];
    }
#pragma unroll
    for (int ni = 0; ni < 2; ++ni) {
        const int nn2 = ni * 16 + fr;
        bh[ni] = *(const short8*)&adb[0][nn2 * KP + fk];
        bl[ni] = *(const short8*)&adb[1][nn2 * KP + fk];
    }
#pragma unroll
    for (int mi = 0; mi < 2; ++mi)
#pragma unroll
        for (int ni = 0; ni < 2; ++ni) {
            acc[mi][ni] = __builtin_amdgcn_mfma_f32_16x16x32_bf16(ah[mi], bh[ni], acc[mi][ni], 0, 0, 0);
            acc[mi][ni] = __builtin_amdgcn_mfma_f32_16x16x32_bf16(ah[mi], bl[ni], acc[mi][ni], 0, 0, 0);
            acc[mi][ni] = __builtin_amdgcn_mfma_f32_16x16x32_bf16(al[mi], bh[ni], acc[mi][ni], 0, 0, 0);
        }
    __syncthreads();   // all xsb/adb reads done; safe to overwrite with os

    // --- epilogue a: acc -> os with exact output-tile layout [t][25] ---
    // D mapping: col u = ntile*16 + (lane&15), row t = mtile*16 + (lane>>4)*4 + r
#pragma unroll
    for (int mi = 0; mi < 2; ++mi) {
        const int tb = (wid * 2 + mi) * 16 + (lane >> 4) * 4;
#pragma unroll
        for (int ni = 0; ni < 2; ++ni) {
            const int u = ni * 16 + fr;
            if (u < VV) {
#pragma unroll
                for (int r = 0; r < 4; ++r)
                    os[(tb + r) * VV + u] = acc[mi][ni][r];
            }
        }
    }
    __syncthreads();

    // --- epilogue b: coalesced float4 stores of the whole 12.8 KB tile ---
    float4* ob4 = (float4*)(out + (size_t)blk * (TT * VV));
    const float4* os4 = (const float4*)os;
    ob4[tid]       = os4[tid];
    ob4[tid + 256] = os4[tid + 256];
    ob4[tid + 512] = os4[tid + 512];
    if (tid < 32) ob4[tid + 768] = os4[tid + 768];
}

// ---------------------------------------------------------------------------
extern "C" void kernel_launch(void* const* d_in, const int* in_sizes, int n_in,
                              void* d_out, int out_size, void* d_ws, size_t ws_size,
                              hipStream_t stream) {
    const float* x   = (const float*)d_in[0];
    const float* A   = (const float*)d_in[1];
    const float* w1  = (const float*)d_in[2];
    const float* b1  = (const float*)d_in[3];
    const float* w2  = (const float*)d_in[4];
    const float* b2  = (const float*)d_in[5];
    const float* w4  = (const float*)d_in[6];
    const float* b4  = (const float*)d_in[7];
    const float* sw1 = (const float*)d_in[8];
    const float* sb1 = (const float*)d_in[9];
    const float* sw2 = (const float*)d_in[10];
    const float* sb2 = (const float*)d_in[11];
    float* out = (float*)d_out;

    float* ws = (float*)d_ws;
    float* xm  = ws;                                 // N*C*V      = 204800
    float* a_s = xm + (size_t)NN * CC * VV;          // N*V        = 3200
    float* rel = a_s + (size_t)NN * VV;              // N*R*V*28   = 716800

    kA_tmean<<<NN * CC, 256, 0, stream>>>(x, xm);
    kB_small<<<NN, 256, 0, stream>>>(xm, w1, b1, w2, b2, sw1, sb1, sw2, sb2, a_s, rel);
    kC_main<<<NN * CC, 256, 0, stream>>>(x, A, w4, b4, rel, a_s, out);
}